// Round 1
// baseline (1211.203 us; speedup 1.0000x reference)
//
#include <hip/hip_runtime.h>
#include <hip/hip_bf16.h>
#include <cstdint>

#define N_NODES 50000
#define N_EDGES 800000
#define HDIM 128
#define EPS_BN 1e-5f

// ---------------- encoder: x(N,19) -> h0(N,96) = [sp(32), fe(64)] ----------------
__global__ __launch_bounds__(128) void encoder_kernel(
    const float* __restrict__ x,
    const float* __restrict__ sp_w1, const float* __restrict__ sp_b1,
    const float* __restrict__ sp_w2, const float* __restrict__ sp_b2,
    const float* __restrict__ fe_w, const float* __restrict__ fe_b,
    float* __restrict__ h0)
{
    __shared__ float w1[96], b1[32], w2[1024], b2[32], wf[1024], bf[64];
    __shared__ float outt[128 * 97];
    int tid = threadIdx.x;
    for (int i = tid; i < 96; i += 128) w1[i] = sp_w1[i];
    for (int i = tid; i < 32; i += 128) { b1[i] = sp_b1[i]; b2[i] = sp_b2[i]; }
    for (int i = tid; i < 1024; i += 128) { w2[i] = sp_w2[i]; wf[i] = fe_w[i]; }
    for (int i = tid; i < 64; i += 128) bf[i] = fe_b[i];
    __syncthreads();
    int n = blockIdx.x * 128 + tid;
    if (n < N_NODES) {
        float c0 = x[n*19+0], c1 = x[n*19+1], c2 = x[n*19+2];
        float ft[16];
        #pragma unroll
        for (int i = 0; i < 16; i++) ft[i] = x[n*19+3+i];
        float t1[32];
        #pragma unroll
        for (int j = 0; j < 32; j++)
            t1[j] = fmaxf(c0*w1[j] + c1*w1[32+j] + c2*w1[64+j] + b1[j], 0.f);
        #pragma unroll 4
        for (int j = 0; j < 32; j++) {
            float a = b2[j];
            #pragma unroll
            for (int k = 0; k < 32; k++) a += t1[k]*w2[k*32+j];
            outt[tid*97+j] = fmaxf(a, 0.f);
        }
        #pragma unroll 4
        for (int j = 0; j < 64; j++) {
            float a = bf[j];
            #pragma unroll
            for (int k = 0; k < 16; k++) a += ft[k]*wf[k*64+j];
            outt[tid*97+32+j] = fmaxf(a, 0.f);
        }
    }
    __syncthreads();
    int base = blockIdx.x * 128;
    int nv = min(128, N_NODES - base);
    for (int i = tid; i < nv*96; i += 128) {
        int r = i / 96, c = i - r*96;
        h0[(size_t)base*96 + i] = outt[r*97 + c];
    }
}

// ---------------- CSR build ----------------
__global__ void deg_kernel(const int* __restrict__ dst, const float* __restrict__ ew,
                           int* __restrict__ cnt, float* __restrict__ degw)
{
    int e = blockIdx.x*256 + threadIdx.x;
    if (e < N_EDGES) {
        int d = dst[e];
        atomicAdd(&cnt[d], 1);
        atomicAdd(&degw[d], ew[e]);
    }
}

__global__ void prep_kernel(const int* __restrict__ cnt, const float* __restrict__ degw,
                            float* __restrict__ inv_cnt, float* __restrict__ dis)
{
    int n = blockIdx.x*256 + threadIdx.x;
    if (n < N_NODES) {
        inv_cnt[n] = 1.f / (float)max(cnt[n], 1);
        dis[n] = rsqrtf(degw[n] + 1.f);   // +1 self-loop weight; always > 0
    }
}

__global__ __launch_bounds__(1024) void scan_kernel(const int* __restrict__ cnt,
                                                    int* __restrict__ rowptr)
{
    __shared__ int lds[1024];
    __shared__ int carry;
    int tid = threadIdx.x;
    if (tid == 0) carry = 0;
    __syncthreads();
    for (int base = 0; base < N_NODES; base += 1024) {
        int i = base + tid;
        int v = (i < N_NODES) ? cnt[i] : 0;
        lds[tid] = v;
        __syncthreads();
        for (int off = 1; off < 1024; off <<= 1) {
            int t = (tid >= off) ? lds[tid-off] : 0;
            __syncthreads();
            lds[tid] += t;
            __syncthreads();
        }
        int incl = lds[tid];
        int c = carry;
        __syncthreads();
        if (tid == 1023) carry = c + incl;
        if (i < N_NODES) rowptr[i] = c + incl - v;
        __syncthreads();
    }
    if (tid == 0) rowptr[N_NODES] = carry;
}

__global__ void scatter_kernel(const int* __restrict__ src, const int* __restrict__ dst,
                               const float* __restrict__ ew,
                               const int* __restrict__ rowptr, int* __restrict__ fill,
                               int* __restrict__ col, float* __restrict__ colw)
{
    int e = blockIdx.x*256 + threadIdx.x;
    if (e < N_EDGES) {
        int d = dst[e];
        int pos = rowptr[d] + atomicAdd(&fill[d], 1);
        col[pos] = src[e];
        colw[pos] = ew[e];
    }
}

// ---------------- aggregation ----------------
// SAGE: out[n][f] = mean over incoming edges of h[src][f]
__global__ __launch_bounds__(128) void sage_agg_kernel(
    const float* __restrict__ h, int ldh, int D,
    const int* __restrict__ rowptr, const int* __restrict__ col,
    const float* __restrict__ inv_cnt,
    float* __restrict__ out, int ldo)
{
    int n = blockIdx.x;
    int f = threadIdx.x;
    if (f >= D) return;
    int beg = rowptr[n], end = rowptr[n+1];
    float acc = 0.f;
    int j = beg;
    for (; j + 3 < end; j += 4) {
        int s0 = col[j], s1 = col[j+1], s2 = col[j+2], s3 = col[j+3];
        float v0 = h[(size_t)s0*ldh+f], v1 = h[(size_t)s1*ldh+f];
        float v2 = h[(size_t)s2*ldh+f], v3 = h[(size_t)s3*ldh+f];
        acc += (v0 + v1) + (v2 + v3);
    }
    for (; j < end; j++) acc += h[(size_t)col[j]*ldh+f];
    out[(size_t)n*ldo+f] = acc * inv_cnt[n];
}

// GCN: out[n][f] = dis[n]*sum_e ew_e*dis[src_e]*h[src_e][f] + dis[n]^2*h[n][f]
__global__ __launch_bounds__(128) void gcn_agg_kernel(
    const float* __restrict__ h,
    const int* __restrict__ rowptr, const int* __restrict__ col,
    const float* __restrict__ colw, const float* __restrict__ dis,
    float* __restrict__ out)
{
    int n = blockIdx.x;
    int f = threadIdx.x;
    int beg = rowptr[n], end = rowptr[n+1];
    float dn = dis[n];
    float acc = 0.f;
    int j = beg;
    for (; j + 3 < end; j += 4) {
        int s0 = col[j], s1 = col[j+1], s2 = col[j+2], s3 = col[j+3];
        float w0 = colw[j]  *dis[s0], w1 = colw[j+1]*dis[s1];
        float w2 = colw[j+2]*dis[s2], w3 = colw[j+3]*dis[s3];
        acc += w0*h[(size_t)s0*128+f] + w1*h[(size_t)s1*128+f]
             + w2*h[(size_t)s2*128+f] + w3*h[(size_t)s3*128+f];
    }
    for (; j < end; j++) {
        int s = col[j];
        acc += colw[j]*dis[s]*h[(size_t)s*128+f];
    }
    out[(size_t)n*128+f] = dn*acc + dn*dn*h[(size_t)n*128+f];
}

// ---------------- GEMM: C = A1@W1 + A2@W2 + bias, optional relu, optional BN stats ----------------
template<int NOUT>
__global__ __launch_bounds__(256) void gemm_kernel(
    const float* __restrict__ A1, int lda1, int K1, const float* __restrict__ W1,
    const float* __restrict__ A2, int lda2, int K2, const float* __restrict__ W2,
    const float* __restrict__ bias,
    float* __restrict__ C, int ldc,
    float* __restrict__ stats, int do_relu)
{
    constexpr int CPT = NOUT / 16;
    __shared__ float A_lds[64][65];
    __shared__ float W_lds[64][NOUT];
    __shared__ float red[2][NOUT];
    int tid = threadIdx.x;
    int tx = tid & 15, ty = tid >> 4;
    int r0 = blockIdx.x * 64;
    float acc[4][CPT];
    #pragma unroll
    for (int rr = 0; rr < 4; rr++)
        #pragma unroll
        for (int cc = 0; cc < CPT; cc++) acc[rr][cc] = 0.f;

    for (int seg = 0; seg < 2; seg++) {
        const float* A = seg ? A2 : A1;
        const float* W = seg ? W2 : W1;
        int K   = seg ? K2 : K1;
        int lda = seg ? lda2 : lda1;
        if (K == 0) continue;
        for (int k0 = 0; k0 < K; k0 += 64) {
            int kc = min(64, K - k0);
            __syncthreads();
            for (int i = tid; i < 64*64; i += 256) {
                int r = i >> 6, kk = i & 63;
                float v = 0.f;
                if (kk < kc && r0 + r < N_NODES) v = A[(size_t)(r0+r)*lda + k0 + kk];
                A_lds[r][kk] = v;
            }
            for (int i = tid; i < 64*NOUT; i += 256) {
                int kk = i / NOUT, jj = i - kk*NOUT;
                W_lds[kk][jj] = (kk < kc) ? W[(size_t)(k0+kk)*NOUT + jj] : 0.f;
            }
            __syncthreads();
            #pragma unroll 4
            for (int kk = 0; kk < 64; kk++) {
                float a[4];
                #pragma unroll
                for (int rr = 0; rr < 4; rr++) a[rr] = A_lds[ty*4+rr][kk];
                float w[CPT];
                #pragma unroll
                for (int cc = 0; cc < CPT; cc++) w[cc] = W_lds[kk][tx*CPT+cc];
                #pragma unroll
                for (int rr = 0; rr < 4; rr++)
                    #pragma unroll
                    for (int cc = 0; cc < CPT; cc++)
                        acc[rr][cc] += a[rr] * w[cc];
            }
        }
    }

    float bj[CPT];
    #pragma unroll
    for (int cc = 0; cc < CPT; cc++) bj[cc] = bias[tx*CPT+cc];
    float s1[CPT], s2[CPT];
    #pragma unroll
    for (int cc = 0; cc < CPT; cc++) { s1[cc] = 0.f; s2[cc] = 0.f; }

    #pragma unroll
    for (int rr = 0; rr < 4; rr++) {
        int r = r0 + ty*4 + rr;
        if (r < N_NODES) {
            float vals[CPT];
            #pragma unroll
            for (int cc = 0; cc < CPT; cc++) {
                float v = acc[rr][cc] + bj[cc];
                if (do_relu) v = fmaxf(v, 0.f);
                vals[cc] = v;
                s1[cc] += v;
                s2[cc] += v*v;
            }
            #pragma unroll
            for (int cc = 0; cc < CPT; cc += 4) {
                float4 o = make_float4(vals[cc], vals[cc+1], vals[cc+2], vals[cc+3]);
                *(float4*)&C[(size_t)r*ldc + tx*CPT + cc] = o;
            }
        }
    }

    if (stats) {
        __syncthreads();
        for (int i = tid; i < 2*NOUT; i += 256) (&red[0][0])[i] = 0.f;
        __syncthreads();
        #pragma unroll
        for (int cc = 0; cc < CPT; cc++) {
            atomicAdd(&red[0][tx*CPT+cc], s1[cc]);
            atomicAdd(&red[1][tx*CPT+cc], s2[cc]);
        }
        __syncthreads();
        for (int i = tid; i < NOUT; i += 256) {
            atomicAdd(&stats[i], red[0][i]);
            atomicAdd(&stats[NOUT+i], red[1][i]);
        }
    }
}

// ---------------- BN + ReLU in place (h is N x 128) ----------------
__global__ __launch_bounds__(256) void bnrelu_kernel(
    float* __restrict__ h, const float* __restrict__ stats,
    const float* __restrict__ g, const float* __restrict__ b)
{
    __shared__ float sc[128], sh[128];
    int tid = threadIdx.x;
    if (tid < 128) {
        float mu  = stats[tid] * (1.f/N_NODES);
        float var = stats[128+tid] * (1.f/N_NODES) - mu*mu;
        float s = g[tid] * rsqrtf(var + EPS_BN);
        sc[tid] = s;
        sh[tid] = b[tid] - mu*s;
    }
    __syncthreads();
    const int total = N_NODES * 32;  // float4 count
    for (int i = blockIdx.x*256 + tid; i < total; i += gridDim.x*256) {
        float4 v = ((float4*)h)[i];
        int c = (i & 31) * 4;
        v.x = fmaxf(v.x*sc[c+0] + sh[c+0], 0.f);
        v.y = fmaxf(v.y*sc[c+1] + sh[c+1], 0.f);
        v.z = fmaxf(v.z*sc[c+2] + sh[c+2], 0.f);
        v.w = fmaxf(v.w*sc[c+3] + sh[c+3], 0.f);
        ((float4*)h)[i] = v;
    }
}

// ---------------- classifier head 2: out = hc(N,64) @ w2(64,10) + b2 ----------------
__global__ __launch_bounds__(128) void cl2_kernel(
    const float* __restrict__ hc, const float* __restrict__ w2,
    const float* __restrict__ b2, float* __restrict__ out)
{
    __shared__ float tile[128][65];
    __shared__ float wl[640];
    __shared__ float bl[16];
    __shared__ float ol[1280];
    int tid = threadIdx.x;
    int base = blockIdx.x * 128;
    int nv = min(128, N_NODES - base);
    for (int i = tid; i < 640; i += 128) wl[i] = w2[i];
    if (tid < 10) bl[tid] = b2[tid];
    for (int i = tid; i < nv*64; i += 128) {
        int r = i >> 6, c = i & 63;
        tile[r][c] = hc[(size_t)base*64 + i];
    }
    __syncthreads();
    if (tid < nv) {
        float o[10];
        #pragma unroll
        for (int j = 0; j < 10; j++) o[j] = bl[j];
        #pragma unroll 4
        for (int k = 0; k < 64; k++) {
            float hv = tile[tid][k];
            #pragma unroll
            for (int j = 0; j < 10; j++) o[j] += hv * wl[k*10+j];
        }
        #pragma unroll
        for (int j = 0; j < 10; j++) ol[tid*10+j] = o[j];
    }
    __syncthreads();
    for (int i = tid; i < nv*10; i += 128) out[(size_t)base*10 + i] = ol[i];
}

// ---------------- launch ----------------
extern "C" void kernel_launch(void* const* d_in, const int* in_sizes, int n_in,
                              void* d_out, int out_size, void* d_ws, size_t ws_size,
                              hipStream_t stream)
{
    const float* x     = (const float*)d_in[0];
    const int*   ei    = (const int*)  d_in[1];
    const float* ew    = (const float*)d_in[2];
    const float* sp_w1 = (const float*)d_in[3];
    const float* sp_b1 = (const float*)d_in[4];
    const float* sp_w2 = (const float*)d_in[5];
    const float* sp_b2 = (const float*)d_in[6];
    const float* fe_w  = (const float*)d_in[7];
    const float* fe_b  = (const float*)d_in[8];
    const float* c1_wl = (const float*)d_in[9];
    const float* c1_wr = (const float*)d_in[10];
    const float* c1_b  = (const float*)d_in[11];
    const float* c2_w  = (const float*)d_in[12];
    const float* c2_b  = (const float*)d_in[13];
    const float* c3_wl = (const float*)d_in[14];
    const float* c3_wr = (const float*)d_in[15];
    const float* c3_b  = (const float*)d_in[16];
    const float* c4_w  = (const float*)d_in[17];
    const float* c4_b  = (const float*)d_in[18];
    const float* bn_g  = (const float*)d_in[19];
    const float* bn_b  = (const float*)d_in[20];
    const float* fu_w  = (const float*)d_in[21];
    const float* fu_b  = (const float*)d_in[22];
    const float* cl_w1 = (const float*)d_in[23];
    const float* cl_b1 = (const float*)d_in[24];
    const float* cl_w2 = (const float*)d_in[25];
    const float* cl_b2 = (const float*)d_in[26];
    const int* src = ei;
    const int* dst = ei + N_EDGES;
    float* out = (float*)d_out;

    char* p = (char*)d_ws;
    auto alloc = [&](size_t bytes) -> char* {
        char* r = p;
        p += (bytes + 255) & ~(size_t)255;
        return r;
    };
    // zeroed region (one memset): cnt, degw, fill, stats
    char* zero_base = p;
    int*   cnt   = (int*)  alloc(N_NODES*4);
    float* degw  = (float*)alloc(N_NODES*4);
    int*   fill  = (int*)  alloc(N_NODES*4);
    float* stats = (float*)alloc(4*256*4);
    size_t zero_bytes = (size_t)(p - zero_base);
    int*   rowptr  = (int*)  alloc((N_NODES+1)*4);
    int*   col     = (int*)  alloc((size_t)N_EDGES*4);
    float* colw    = (float*)alloc((size_t)N_EDGES*4);
    float* inv_cnt = (float*)alloc(N_NODES*4);
    float* dis     = (float*)alloc(N_NODES*4);
    float* h0      = (float*)alloc((size_t)N_NODES*96*4);
    float* AGG     = (float*)alloc((size_t)N_NODES*128*4);
    float* H1      = (float*)alloc((size_t)N_NODES*128*4);
    float* H2      = (float*)alloc((size_t)N_NODES*128*4);
    float* H3      = (float*)alloc((size_t)N_NODES*128*4);
    float* H4 = H3;  // H3 dead after conv4 aggregation
    float* HF = H1;  // H1 dead after conv2 aggregation
    float* HC = h0;  // h0 dead after conv1 GEMM (N*64*4 < N*96*4)

    hipMemsetAsync(zero_base, 0, zero_bytes, stream);

    encoder_kernel<<<391, 128, 0, stream>>>(x, sp_w1, sp_b1, sp_w2, sp_b2, fe_w, fe_b, h0);
    deg_kernel<<<(N_EDGES+255)/256, 256, 0, stream>>>(dst, ew, cnt, degw);
    prep_kernel<<<(N_NODES+255)/256, 256, 0, stream>>>(cnt, degw, inv_cnt, dis);
    scan_kernel<<<1, 1024, 0, stream>>>(cnt, rowptr);
    scatter_kernel<<<(N_EDGES+255)/256, 256, 0, stream>>>(src, dst, ew, rowptr, fill, col, colw);

    // conv1 (SAGE, in 96 -> 128)
    sage_agg_kernel<<<N_NODES, 128, 0, stream>>>(h0, 96, 96, rowptr, col, inv_cnt, AGG, 96);
    gemm_kernel<128><<<782, 256, 0, stream>>>(AGG, 96, 96, c1_wl, h0, 96, 96, c1_wr,
                                              c1_b, H1, 128, stats + 0, 0);
    bnrelu_kernel<<<1024, 256, 0, stream>>>(H1, stats + 0, bn_g + 0, bn_b + 0);

    // conv2 (GCN, 128 -> 128)
    gcn_agg_kernel<<<N_NODES, 128, 0, stream>>>(H1, rowptr, col, colw, dis, AGG);
    gemm_kernel<128><<<782, 256, 0, stream>>>(AGG, 128, 128, c2_w, nullptr, 0, 0, nullptr,
                                              c2_b, H2, 128, stats + 256, 0);
    bnrelu_kernel<<<1024, 256, 0, stream>>>(H2, stats + 256, bn_g + 128, bn_b + 128);

    // conv3 (SAGE, 128 -> 128)
    sage_agg_kernel<<<N_NODES, 128, 0, stream>>>(H2, 128, 128, rowptr, col, inv_cnt, AGG, 128);
    gemm_kernel<128><<<782, 256, 0, stream>>>(AGG, 128, 128, c3_wl, H2, 128, 128, c3_wr,
                                              c3_b, H3, 128, stats + 512, 0);
    bnrelu_kernel<<<1024, 256, 0, stream>>>(H3, stats + 512, bn_g + 256, bn_b + 256);

    // conv4 (GCN, 128 -> 128)
    gcn_agg_kernel<<<N_NODES, 128, 0, stream>>>(H3, rowptr, col, colw, dis, AGG);
    gemm_kernel<128><<<782, 256, 0, stream>>>(AGG, 128, 128, c4_w, nullptr, 0, 0, nullptr,
                                              c4_b, H4, 128, stats + 768, 0);
    bnrelu_kernel<<<1024, 256, 0, stream>>>(H4, stats + 768, bn_g + 384, bn_b + 384);

    // fuse: HF = [H2, H4] @ fu_w + fu_b   (no relu, no BN)
    gemm_kernel<128><<<782, 256, 0, stream>>>(H2, 128, 128, fu_w, H4, 128, 128, fu_w + 128*128,
                                              fu_b, HF, 128, nullptr, 0);
    // cl1: HC = relu(HF @ cl_w1 + cl_b1)
    gemm_kernel<64><<<782, 256, 0, stream>>>(HF, 128, 128, cl_w1, nullptr, 0, 0, nullptr,
                                             cl_b1, HC, 64, nullptr, 1);
    // cl2: out = HC @ cl_w2 + cl_b2
    cl2_kernel<<<391, 128, 0, stream>>>(HC, cl_w2, cl_b2, out);
}

// Round 2
// 542.805 us; speedup vs baseline: 2.2314x; 2.2314x over previous
//
#include <hip/hip_runtime.h>
#include <hip/hip_bf16.h>
#include <cstdint>

#define N_NODES 50000
#define N_EDGES 800000
#define EPS_BN 1e-5f

typedef short s16x8 __attribute__((ext_vector_type(8)));   // 8 bf16 = 4 VGPRs
typedef float f32x4 __attribute__((ext_vector_type(4)));

__device__ __forceinline__ ushort f2b(float f) {
    uint u = __float_as_uint(f);
    u += 0x7fffu + ((u >> 16) & 1u);
    return (ushort)(u >> 16);
}
__device__ __forceinline__ float b2f(ushort b) {
    return __uint_as_float(((uint)b) << 16);
}

// ---------------- encoder: x(N,19) -> h0(N,96) bf16 = [sp(32), fe(64)] ----------------
__global__ __launch_bounds__(128) void encoder_kernel(
    const float* __restrict__ x,
    const float* __restrict__ sp_w1, const float* __restrict__ sp_b1,
    const float* __restrict__ sp_w2, const float* __restrict__ sp_b2,
    const float* __restrict__ fe_w, const float* __restrict__ fe_b,
    ushort* __restrict__ h0)
{
    __shared__ float w1[96], b1[32], w2[1024], b2[32], wf[1024], bf[64];
    __shared__ float outt[128 * 97];
    int tid = threadIdx.x;
    for (int i = tid; i < 96; i += 128) w1[i] = sp_w1[i];
    for (int i = tid; i < 32; i += 128) { b1[i] = sp_b1[i]; b2[i] = sp_b2[i]; }
    for (int i = tid; i < 1024; i += 128) { w2[i] = sp_w2[i]; wf[i] = fe_w[i]; }
    for (int i = tid; i < 64; i += 128) bf[i] = fe_b[i];
    __syncthreads();
    int n = blockIdx.x * 128 + tid;
    if (n < N_NODES) {
        float c0 = x[n*19+0], c1 = x[n*19+1], c2 = x[n*19+2];
        float ft[16];
        #pragma unroll
        for (int i = 0; i < 16; i++) ft[i] = x[n*19+3+i];
        float t1[32];
        #pragma unroll
        for (int j = 0; j < 32; j++)
            t1[j] = fmaxf(c0*w1[j] + c1*w1[32+j] + c2*w1[64+j] + b1[j], 0.f);
        #pragma unroll 4
        for (int j = 0; j < 32; j++) {
            float a = b2[j];
            #pragma unroll
            for (int k = 0; k < 32; k++) a += t1[k]*w2[k*32+j];
            outt[tid*97+j] = fmaxf(a, 0.f);
        }
        #pragma unroll 4
        for (int j = 0; j < 64; j++) {
            float a = bf[j];
            #pragma unroll
            for (int k = 0; k < 16; k++) a += ft[k]*wf[k*64+j];
            outt[tid*97+32+j] = fmaxf(a, 0.f);
        }
    }
    __syncthreads();
    int base = blockIdx.x * 128;
    int nv = min(128, N_NODES - base);
    for (int i = tid; i < nv*96; i += 128) {
        int r = i / 96, c = i - r*96;
        h0[(size_t)base*96 + i] = f2b(outt[r*97 + c]);
    }
}

// ---------------- CSR build ----------------
__global__ void deg_kernel(const int* __restrict__ dst, const float* __restrict__ ew,
                           int* __restrict__ cnt, float* __restrict__ degw)
{
    int e = blockIdx.x*256 + threadIdx.x;
    if (e < N_EDGES) {
        int d = dst[e];
        atomicAdd(&cnt[d], 1);
        atomicAdd(&degw[d], ew[e]);
    }
}

__global__ void prep_kernel(const int* __restrict__ cnt, const float* __restrict__ degw,
                            float* __restrict__ inv_cnt, float* __restrict__ dis)
{
    int n = blockIdx.x*256 + threadIdx.x;
    if (n < N_NODES) {
        inv_cnt[n] = 1.f / (float)max(cnt[n], 1);
        dis[n] = rsqrtf(degw[n] + 1.f);   // +1 self-loop weight; always > 0
    }
}

// scan phase A: per-1024 chunk exclusive scan + chunk totals
__global__ __launch_bounds__(1024) void scan_a(const int* __restrict__ cnt,
                                               int* __restrict__ rowptr,
                                               int* __restrict__ bsum)
{
    __shared__ int wsum[16];
    int tid = threadIdx.x;
    int i = blockIdx.x*1024 + tid;
    int v = (i < N_NODES) ? cnt[i] : 0;
    int lane = tid & 63, wid = tid >> 6;
    int incl = v;
    #pragma unroll
    for (int off = 1; off < 64; off <<= 1) {
        int t = __shfl_up(incl, off);
        if (lane >= off) incl += t;
    }
    if (lane == 63) wsum[wid] = incl;
    __syncthreads();
    if (wid == 0 && lane < 16) {
        int s = wsum[lane];
        #pragma unroll
        for (int off = 1; off < 16; off <<= 1) {
            int t = __shfl_up(s, off);
            if (lane >= off) s += t;
        }
        wsum[lane] = s;
    }
    __syncthreads();
    int base = (wid > 0) ? wsum[wid-1] : 0;
    if (i < N_NODES) rowptr[i] = base + incl - v;
    if (tid == 1023) bsum[blockIdx.x] = base + incl;
}

// scan phase B: scan of 49 chunk totals (one wave)
__global__ void scan_b(const int* __restrict__ bsum, int* __restrict__ boff)
{
    const int NC = (N_NODES + 1023) >> 10;   // 49
    int lane = threadIdx.x;
    int v = (lane < NC) ? bsum[lane] : 0;
    int incl = v;
    #pragma unroll
    for (int off = 1; off < 64; off <<= 1) {
        int t = __shfl_up(incl, off);
        if (lane >= off) incl += t;
    }
    if (lane <= NC) boff[lane] = incl - v;   // exclusive; boff[NC] = grand total
}

// scan phase C: add chunk offsets; rowptr[N] = total
__global__ void scan_c(int* __restrict__ rowptr, const int* __restrict__ boff)
{
    int i = blockIdx.x*256 + threadIdx.x;
    if (i < N_NODES) rowptr[i] += boff[i >> 10];
    else if (i == N_NODES) rowptr[i] = boff[(N_NODES + 1023) >> 10];
}

// scatter: colw = ew * dis[src]  (GCN pre-normalization baked in)
__global__ void scatter_kernel(const int* __restrict__ src, const int* __restrict__ dst,
                               const float* __restrict__ ew, const float* __restrict__ dis,
                               const int* __restrict__ rowptr, int* __restrict__ fill,
                               int* __restrict__ col, float* __restrict__ colw)
{
    int e = blockIdx.x*256 + threadIdx.x;
    if (e < N_EDGES) {
        int d = dst[e];
        int s = src[e];
        int pos = rowptr[d] + atomicAdd(&fill[d], 1);
        col[pos] = s;
        colw[pos] = ew[e] * dis[s];
    }
}

// ---------------- aggregation (bf16 h, one wave per node, lane = 2 feats) ----------------
__global__ __launch_bounds__(256) void sage_agg(
    const ushort* __restrict__ h, int ldh, int D2,
    const int* __restrict__ rowptr, const int* __restrict__ col,
    const float* __restrict__ inv_cnt,
    ushort* __restrict__ out, int ldo)
{
    int w = threadIdx.x >> 6, l = threadIdx.x & 63;
    int n = blockIdx.x*4 + w;
    if (n >= N_NODES) return;
    int beg = rowptr[n], end = rowptr[n+1];
    bool act = l < D2;
    int off = 2*l;
    float ax = 0.f, ay = 0.f;
    int j = beg;
    for (; j + 3 < end; j += 4) {
        int s0 = col[j], s1 = col[j+1], s2 = col[j+2], s3 = col[j+3];
        if (act) {
            uint u0 = *(const uint*)(h + (size_t)s0*ldh + off);
            uint u1 = *(const uint*)(h + (size_t)s1*ldh + off);
            uint u2 = *(const uint*)(h + (size_t)s2*ldh + off);
            uint u3 = *(const uint*)(h + (size_t)s3*ldh + off);
            ax += __uint_as_float(u0<<16) + __uint_as_float(u1<<16)
                + __uint_as_float(u2<<16) + __uint_as_float(u3<<16);
            ay += __uint_as_float(u0 & 0xffff0000u) + __uint_as_float(u1 & 0xffff0000u)
                + __uint_as_float(u2 & 0xffff0000u) + __uint_as_float(u3 & 0xffff0000u);
        }
    }
    for (; j < end; j++) {
        int s = col[j];
        if (act) {
            uint u = *(const uint*)(h + (size_t)s*ldh + off);
            ax += __uint_as_float(u<<16);
            ay += __uint_as_float(u & 0xffff0000u);
        }
    }
    if (act) {
        float ic = inv_cnt[n];
        uint o = (uint)f2b(ax*ic) | ((uint)f2b(ay*ic) << 16);
        *(uint*)(out + (size_t)n*ldo + off) = o;
    }
}

__global__ __launch_bounds__(256) void gcn_agg(
    const ushort* __restrict__ h,
    const int* __restrict__ rowptr, const int* __restrict__ col,
    const float* __restrict__ colw, const float* __restrict__ dis,
    ushort* __restrict__ out)
{
    int w = threadIdx.x >> 6, l = threadIdx.x & 63;
    int n = blockIdx.x*4 + w;
    if (n >= N_NODES) return;
    int beg = rowptr[n], end = rowptr[n+1];
    int off = 2*l;
    float ax = 0.f, ay = 0.f;
    int j = beg;
    for (; j + 3 < end; j += 4) {
        int s0 = col[j], s1 = col[j+1], s2 = col[j+2], s3 = col[j+3];
        float w0 = colw[j], w1 = colw[j+1], w2 = colw[j+2], w3 = colw[j+3];
        uint u0 = *(const uint*)(h + (size_t)s0*128 + off);
        uint u1 = *(const uint*)(h + (size_t)s1*128 + off);
        uint u2 = *(const uint*)(h + (size_t)s2*128 + off);
        uint u3 = *(const uint*)(h + (size_t)s3*128 + off);
        ax += w0*__uint_as_float(u0<<16) + w1*__uint_as_float(u1<<16)
            + w2*__uint_as_float(u2<<16) + w3*__uint_as_float(u3<<16);
        ay += w0*__uint_as_float(u0 & 0xffff0000u) + w1*__uint_as_float(u1 & 0xffff0000u)
            + w2*__uint_as_float(u2 & 0xffff0000u) + w3*__uint_as_float(u3 & 0xffff0000u);
    }
    for (; j < end; j++) {
        int s = col[j];
        float wj = colw[j];
        uint u = *(const uint*)(h + (size_t)s*128 + off);
        ax += wj*__uint_as_float(u<<16);
        ay += wj*__uint_as_float(u & 0xffff0000u);
    }
    float dn = dis[n];
    uint us = *(const uint*)(h + (size_t)n*128 + off);
    float sx = __uint_as_float(us<<16), sy = __uint_as_float(us & 0xffff0000u);
    float rx = dn*ax + dn*dn*sx;
    float ry = dn*ay + dn*dn*sy;
    uint o = (uint)f2b(rx) | ((uint)f2b(ry) << 16);
    *(uint*)(out + (size_t)n*128 + off) = o;
}

// ---------------- weight prep: W[k][col] fp32 (2 segs) -> Wt[col][KT] bf16 ----------------
__global__ void prep_w(const float* __restrict__ w1, const float* __restrict__ w2,
                       int K1, int KT, int NOUT, ushort* __restrict__ dst)
{
    int idx = blockIdx.x*256 + threadIdx.x;
    if (idx >= KT*NOUT) return;
    int k = idx / NOUT, c = idx - k*NOUT;
    float v = (k < K1) ? w1[idx] : w2[idx - K1*NOUT];
    dst[c*KT + k] = f2b(v);
}

// ---------------- MFMA GEMM: C = [A1|A2] @ W + bias (bf16 in, bf16 out, fp32 acc) -----
// A-frag: row = lane&15, k = 8*(lane>>4)+j  (16B/lane direct global load)
// B-frag: col = lane&15, k = 8*(lane>>4)+j  (from Wt[col][KT], 16B/lane)
// D-frag: col = lane&15, row = (lane>>4)*4+reg   [verified layout]
template<int KT, int K1, int NOUT, bool RELU, bool STATS>
__global__ __launch_bounds__(256, 2) void gemm_mfma(
    const ushort* __restrict__ A1, int lda1,
    const ushort* __restrict__ A2, int lda2,
    const ushort* __restrict__ Wt,
    const float* __restrict__ bias,
    ushort* __restrict__ C, int ldc,
    float* __restrict__ stats)
{
    constexpr int NCF = NOUT/16;
    constexpr int NKS = KT/32;
    __shared__ float red[2][NOUT];
    int tid = threadIdx.x;
    int w = tid >> 6, l = tid & 63;
    int l15 = l & 15, l4 = l >> 4;
    int r0 = blockIdx.x*128 + w*32;

    const ushort* pa1[2]; const ushort* pa2[2];
    #pragma unroll
    for (int rf = 0; rf < 2; rf++) {
        int rc = min(r0 + rf*16 + l15, N_NODES-1);
        pa1[rf] = A1 + (size_t)rc*lda1 + 8*l4;
        pa2[rf] = A2 + (size_t)rc*lda2 + 8*l4;
    }
    const ushort* pw = Wt + (size_t)l15*KT + 8*l4;

    f32x4 acc[2][NCF];
    #pragma unroll
    for (int rf = 0; rf < 2; rf++)
        #pragma unroll
        for (int cf = 0; cf < NCF; cf++)
            acc[rf][cf] = (f32x4){0.f, 0.f, 0.f, 0.f};

    #pragma unroll
    for (int ks = 0; ks < NKS; ks++) {
        const int k0 = ks*32;
        s16x8 a[2];
        #pragma unroll
        for (int rf = 0; rf < 2; rf++) {
            const ushort* p = (k0 < K1) ? (pa1[rf] + k0) : (pa2[rf] + (k0 - K1));
            a[rf] = *(const s16x8*)p;
        }
        s16x8 b[NCF];
        #pragma unroll
        for (int cf = 0; cf < NCF; cf++)
            b[cf] = *(const s16x8*)(pw + (size_t)cf*16*KT + k0);
        #pragma unroll
        for (int rf = 0; rf < 2; rf++)
            #pragma unroll
            for (int cf = 0; cf < NCF; cf++)
                acc[rf][cf] = __builtin_amdgcn_mfma_f32_16x16x32_bf16(a[rf], b[cf], acc[rf][cf], 0, 0, 0);
    }

    float s1l[NCF], s2l[NCF];
    #pragma unroll
    for (int cf = 0; cf < NCF; cf++) { s1l[cf] = 0.f; s2l[cf] = 0.f; }

    #pragma unroll
    for (int cf = 0; cf < NCF; cf++) {
        int colc = cf*16 + l15;
        float bv = bias[colc];
        #pragma unroll
        for (int rf = 0; rf < 2; rf++) {
            int rb = r0 + rf*16 + l4*4;
            #pragma unroll
            for (int reg = 0; reg < 4; reg++) {
                int r = rb + reg;
                if (r < N_NODES) {
                    float v = acc[rf][cf][reg] + bv;
                    if (RELU) v = fmaxf(v, 0.f);
                    C[(size_t)r*ldc + colc] = f2b(v);
                    if (STATS) { s1l[cf] += v; s2l[cf] += v*v; }
                }
            }
        }
    }

    if (STATS) {
        for (int i = tid; i < 2*NOUT; i += 256) (&red[0][0])[i] = 0.f;
        __syncthreads();
        #pragma unroll
        for (int cf = 0; cf < NCF; cf++) {
            atomicAdd(&red[0][cf*16 + l15], s1l[cf]);
            atomicAdd(&red[1][cf*16 + l15], s2l[cf]);
        }
        __syncthreads();
        for (int i = tid; i < NOUT; i += 256) {
            atomicAdd(&stats[i], red[0][i]);
            atomicAdd(&stats[NOUT+i], red[1][i]);
        }
    }
}

// ---------------- BN + ReLU in place on bf16 (N x 128) ----------------
__global__ __launch_bounds__(256) void bnrelu_kernel(
    ushort* __restrict__ h, const float* __restrict__ stats,
    const float* __restrict__ g, const float* __restrict__ b)
{
    __shared__ float sc[128], sh[128];
    int tid = threadIdx.x;
    if (tid < 128) {
        float mu  = stats[tid] * (1.f/N_NODES);
        float var = stats[128+tid] * (1.f/N_NODES) - mu*mu;
        float s = g[tid] * rsqrtf(var + EPS_BN);
        sc[tid] = s;
        sh[tid] = b[tid] - mu*s;
    }
    __syncthreads();
    const int total = N_NODES * 16;   // uint4 chunks of 8 bf16
    for (int i = blockIdx.x*256 + tid; i < total; i += gridDim.x*256) {
        uint4 u = ((const uint4*)h)[i];
        int c = (i & 15) * 8;
        float v0 = __uint_as_float(u.x<<16),  v1 = __uint_as_float(u.x & 0xffff0000u);
        float v2 = __uint_as_float(u.y<<16),  v3 = __uint_as_float(u.y & 0xffff0000u);
        float v4 = __uint_as_float(u.z<<16),  v5 = __uint_as_float(u.z & 0xffff0000u);
        float v6 = __uint_as_float(u.w<<16),  v7 = __uint_as_float(u.w & 0xffff0000u);
        v0 = fmaxf(v0*sc[c+0] + sh[c+0], 0.f);
        v1 = fmaxf(v1*sc[c+1] + sh[c+1], 0.f);
        v2 = fmaxf(v2*sc[c+2] + sh[c+2], 0.f);
        v3 = fmaxf(v3*sc[c+3] + sh[c+3], 0.f);
        v4 = fmaxf(v4*sc[c+4] + sh[c+4], 0.f);
        v5 = fmaxf(v5*sc[c+5] + sh[c+5], 0.f);
        v6 = fmaxf(v6*sc[c+6] + sh[c+6], 0.f);
        v7 = fmaxf(v7*sc[c+7] + sh[c+7], 0.f);
        u.x = (uint)f2b(v0) | ((uint)f2b(v1)<<16);
        u.y = (uint)f2b(v2) | ((uint)f2b(v3)<<16);
        u.z = (uint)f2b(v4) | ((uint)f2b(v5)<<16);
        u.w = (uint)f2b(v6) | ((uint)f2b(v7)<<16);
        ((uint4*)h)[i] = u;
    }
}

// ---------------- classifier head 2: out = hc(N,64)bf16 @ w2(64,10) + b2 -> fp32 ----------
__global__ __launch_bounds__(128) void cl2_kernel(
    const ushort* __restrict__ hc, const float* __restrict__ w2,
    const float* __restrict__ b2, float* __restrict__ out)
{
    __shared__ float tile[128][65];
    __shared__ float wl[640];
    __shared__ float bl[16];
    __shared__ float ol[1280];
    int tid = threadIdx.x;
    int base = blockIdx.x * 128;
    int nv = min(128, N_NODES - base);
    for (int i = tid; i < 640; i += 128) wl[i] = w2[i];
    if (tid < 10) bl[tid] = b2[tid];
    for (int i = tid; i < nv*64; i += 128) {
        int r = i >> 6, c = i & 63;
        tile[r][c] = b2f(hc[(size_t)base*64 + i]);
    }
    __syncthreads();
    if (tid < nv) {
        float o[10];
        #pragma unroll
        for (int j = 0; j < 10; j++) o[j] = bl[j];
        #pragma unroll 4
        for (int k = 0; k < 64; k++) {
            float hv = tile[tid][k];
            #pragma unroll
            for (int j = 0; j < 10; j++) o[j] += hv * wl[k*10+j];
        }
        #pragma unroll
        for (int j = 0; j < 10; j++) ol[tid*10+j] = o[j];
    }
    __syncthreads();
    for (int i = tid; i < nv*10; i += 128) out[(size_t)base*10 + i] = ol[i];
}

// ---------------- launch ----------------
extern "C" void kernel_launch(void* const* d_in, const int* in_sizes, int n_in,
                              void* d_out, int out_size, void* d_ws, size_t ws_size,
                              hipStream_t stream)
{
    const float* x     = (const float*)d_in[0];
    const int*   ei    = (const int*)  d_in[1];
    const float* ew    = (const float*)d_in[2];
    const float* sp_w1 = (const float*)d_in[3];
    const float* sp_b1 = (const float*)d_in[4];
    const float* sp_w2 = (const float*)d_in[5];
    const float* sp_b2 = (const float*)d_in[6];
    const float* fe_w  = (const float*)d_in[7];
    const float* fe_b  = (const float*)d_in[8];
    const float* c1_wl = (const float*)d_in[9];
    const float* c1_wr = (const float*)d_in[10];
    const float* c1_b  = (const float*)d_in[11];
    const float* c2_w  = (const float*)d_in[12];
    const float* c2_b  = (const float*)d_in[13];
    const float* c3_wl = (const float*)d_in[14];
    const float* c3_wr = (const float*)d_in[15];
    const float* c3_b  = (const float*)d_in[16];
    const float* c4_w  = (const float*)d_in[17];
    const float* c4_b  = (const float*)d_in[18];
    const float* bn_g  = (const float*)d_in[19];
    const float* bn_b  = (const float*)d_in[20];
    const float* fu_w  = (const float*)d_in[21];
    const float* fu_b  = (const float*)d_in[22];
    const float* cl_w1 = (const float*)d_in[23];
    const float* cl_b1 = (const float*)d_in[24];
    const float* cl_w2 = (const float*)d_in[25];
    const float* cl_b2 = (const float*)d_in[26];
    const int* src = ei;
    const int* dst = ei + N_EDGES;
    float* out = (float*)d_out;

    char* p = (char*)d_ws;
    auto alloc = [&](size_t bytes) -> char* {
        char* r = p;
        p += (bytes + 255) & ~(size_t)255;
        return r;
    };
    // zeroed region: cnt, fill, degw, stats
    char* zero_base = p;
    int*   cnt   = (int*)  alloc(N_NODES*4);
    float* degw  = (float*)alloc(N_NODES*4);
    int*   fill  = (int*)  alloc(N_NODES*4);
    float* stats = (float*)alloc(4*256*4);
    size_t zero_bytes = (size_t)(p - zero_base);
    int*   rowptr  = (int*)  alloc((N_NODES+1)*4);
    int*   bsum    = (int*)  alloc(64*4);
    int*   boff    = (int*)  alloc(64*4);
    int*   col     = (int*)  alloc((size_t)N_EDGES*4);
    float* colw    = (float*)alloc((size_t)N_EDGES*4);
    float* inv_cnt = (float*)alloc(N_NODES*4);
    float* dis     = (float*)alloc(N_NODES*4);
    ushort* wt1  = (ushort*)alloc(192*128*2);
    ushort* wt2  = (ushort*)alloc(128*128*2);
    ushort* wt3  = (ushort*)alloc(256*128*2);
    ushort* wt4  = (ushort*)alloc(128*128*2);
    ushort* wtF  = (ushort*)alloc(256*128*2);
    ushort* wtC1 = (ushort*)alloc(128*64*2);
    ushort* h0  = (ushort*)alloc((size_t)N_NODES*96*2);
    ushort* AGG = (ushort*)alloc((size_t)N_NODES*128*2);
    ushort* H1  = (ushort*)alloc((size_t)N_NODES*128*2);
    ushort* H2  = (ushort*)alloc((size_t)N_NODES*128*2);
    ushort* H3  = (ushort*)alloc((size_t)N_NODES*128*2);
    ushort* H4 = H3;   // H3 dead after conv4 aggregation
    ushort* HF = H1;   // H1 dead after conv2 aggregation
    ushort* HC = h0;   // h0 dead after conv1 GEMM (N*64 <= N*96)

    hipMemsetAsync(zero_base, 0, zero_bytes, stream);

    // weight prep (tiny, 6 launches)
    prep_w<<<(192*128+255)/256, 256, 0, stream>>>(c1_wl, c1_wr, 96, 192, 128, wt1);
    prep_w<<<(128*128+255)/256, 256, 0, stream>>>(c2_w, c2_w, 128, 128, 128, wt2);
    prep_w<<<(256*128+255)/256, 256, 0, stream>>>(c3_wl, c3_wr, 128, 256, 128, wt3);
    prep_w<<<(128*128+255)/256, 256, 0, stream>>>(c4_w, c4_w, 128, 128, 128, wt4);
    prep_w<<<(256*128+255)/256, 256, 0, stream>>>(fu_w, fu_w + 128*128, 128, 256, 128, wtF);
    prep_w<<<(128*64+255)/256, 256, 0, stream>>>(cl_w1, cl_w1, 128, 128, 64, wtC1);

    encoder_kernel<<<391, 128, 0, stream>>>(x, sp_w1, sp_b1, sp_w2, sp_b2, fe_w, fe_b, h0);

    // CSR
    deg_kernel<<<(N_EDGES+255)/256, 256, 0, stream>>>(dst, ew, cnt, degw);
    prep_kernel<<<(N_NODES+255)/256, 256, 0, stream>>>(cnt, degw, inv_cnt, dis);
    scan_a<<<(N_NODES+1023)/1024, 1024, 0, stream>>>(cnt, rowptr, bsum);
    scan_b<<<1, 64, 0, stream>>>(bsum, boff);
    scan_c<<<(N_NODES+256)/256, 256, 0, stream>>>(rowptr, boff);
    scatter_kernel<<<(N_EDGES+255)/256, 256, 0, stream>>>(src, dst, ew, dis, rowptr, fill, col, colw);

    const int GG = (N_NODES + 127) / 128;   // 391
    const int GA = (N_NODES + 3) / 4;       // 12500

    // conv1 (SAGE, 96 -> 128)
    sage_agg<<<GA, 256, 0, stream>>>(h0, 96, 48, rowptr, col, inv_cnt, AGG, 96);
    gemm_mfma<192,96,128,false,true><<<GG, 256, 0, stream>>>(AGG, 96, h0, 96, wt1, c1_b, H1, 128, stats + 0);
    bnrelu_kernel<<<1024, 256, 0, stream>>>(H1, stats + 0, bn_g + 0, bn_b + 0);

    // conv2 (GCN, 128 -> 128)
    gcn_agg<<<GA, 256, 0, stream>>>(H1, rowptr, col, colw, dis, AGG);
    gemm_mfma<128,128,128,false,true><<<GG, 256, 0, stream>>>(AGG, 128, AGG, 128, wt2, c2_b, H2, 128, stats + 256);
    bnrelu_kernel<<<1024, 256, 0, stream>>>(H2, stats + 256, bn_g + 128, bn_b + 128);

    // conv3 (SAGE, 128 -> 128)
    sage_agg<<<GA, 256, 0, stream>>>(H2, 128, 64, rowptr, col, inv_cnt, AGG, 128);
    gemm_mfma<256,128,128,false,true><<<GG, 256, 0, stream>>>(AGG, 128, H2, 128, wt3, c3_b, H3, 128, stats + 512);
    bnrelu_kernel<<<1024, 256, 0, stream>>>(H3, stats + 512, bn_g + 256, bn_b + 256);

    // conv4 (GCN, 128 -> 128)
    gcn_agg<<<GA, 256, 0, stream>>>(H3, rowptr, col, colw, dis, AGG);
    gemm_mfma<128,128,128,false,true><<<GG, 256, 0, stream>>>(AGG, 128, AGG, 128, wt4, c4_b, H4, 128, stats + 768);
    bnrelu_kernel<<<1024, 256, 0, stream>>>(H4, stats + 768, bn_g + 384, bn_b + 384);

    // fuse: HF = [H2, H4] @ fu_w + fu_b
    gemm_mfma<256,128,128,false,false><<<GG, 256, 0, stream>>>(H2, 128, H4, 128, wtF, fu_b, HF, 128, nullptr);
    // cl1: HC = relu(HF @ cl_w1 + cl_b1)
    gemm_mfma<128,128,64,true,false><<<GG, 256, 0, stream>>>(HF, 128, HF, 128, wtC1, cl_b1, HC, 64, nullptr);
    // cl2
    cl2_kernel<<<391, 128, 0, stream>>>(HC, cl_w2, cl_b2, out);
}

// Round 3
// 460.016 us; speedup vs baseline: 2.6330x; 1.1800x over previous
//
#include <hip/hip_runtime.h>
#include <hip/hip_bf16.h>
#include <cstdint>

#define N_NODES 50000
#define N_EDGES 800000
#define EPS_BN 1e-5f

typedef short s16x8 __attribute__((ext_vector_type(8)));   // 8 bf16 = 4 VGPRs
typedef float f32x4 __attribute__((ext_vector_type(4)));

__device__ __forceinline__ ushort f2b(float f) {
    uint u = __float_as_uint(f);
    u += 0x7fffu + ((u >> 16) & 1u);
    return (ushort)(u >> 16);
}
__device__ __forceinline__ float b2f(ushort b) {
    return __uint_as_float(((uint)b) << 16);
}

// ---------------- encoder: x(N,19) -> h0(N,96) bf16 = [sp(32), fe(64)] ----------------
__global__ __launch_bounds__(128) void encoder_kernel(
    const float* __restrict__ x,
    const float* __restrict__ sp_w1, const float* __restrict__ sp_b1,
    const float* __restrict__ sp_w2, const float* __restrict__ sp_b2,
    const float* __restrict__ fe_w, const float* __restrict__ fe_b,
    ushort* __restrict__ h0)
{
    __shared__ float w1[96], b1[32], w2[1024], b2[32], wf[1024], bf[64];
    __shared__ float outt[128 * 97];
    int tid = threadIdx.x;
    for (int i = tid; i < 96; i += 128) w1[i] = sp_w1[i];
    for (int i = tid; i < 32; i += 128) { b1[i] = sp_b1[i]; b2[i] = sp_b2[i]; }
    for (int i = tid; i < 1024; i += 128) { w2[i] = sp_w2[i]; wf[i] = fe_w[i]; }
    for (int i = tid; i < 64; i += 128) bf[i] = fe_b[i];
    __syncthreads();
    int n = blockIdx.x * 128 + tid;
    if (n < N_NODES) {
        float c0 = x[n*19+0], c1 = x[n*19+1], c2 = x[n*19+2];
        float ft[16];
        #pragma unroll
        for (int i = 0; i < 16; i++) ft[i] = x[n*19+3+i];
        float t1[32];
        #pragma unroll
        for (int j = 0; j < 32; j++)
            t1[j] = fmaxf(c0*w1[j] + c1*w1[32+j] + c2*w1[64+j] + b1[j], 0.f);
        #pragma unroll 4
        for (int j = 0; j < 32; j++) {
            float a = b2[j];
            #pragma unroll
            for (int k = 0; k < 32; k++) a += t1[k]*w2[k*32+j];
            outt[tid*97+j] = fmaxf(a, 0.f);
        }
        #pragma unroll 4
        for (int j = 0; j < 64; j++) {
            float a = bf[j];
            #pragma unroll
            for (int k = 0; k < 16; k++) a += ft[k]*wf[k*64+j];
            outt[tid*97+32+j] = fmaxf(a, 0.f);
        }
    }
    __syncthreads();
    int base = blockIdx.x * 128;
    int nv = min(128, N_NODES - base);
    for (int i = tid; i < nv*96; i += 128) {
        int r = i / 96, c = i - r*96;
        h0[(size_t)base*96 + i] = f2b(outt[r*97 + c]);
    }
}

// ---------------- CSR build ----------------
// One packed 64-bit atomic per edge: count in bits [40,64), degw in 23.0 fixed point
// below (max sum ~2^30 << 2^40, no carry into count). Returned old>>40 = edge rank.
__global__ void deg_kernel(const int* __restrict__ dst, const float* __restrict__ ew,
                           unsigned long long* __restrict__ pk, int* __restrict__ rank)
{
    int e = blockIdx.x*256 + threadIdx.x;
    if (e < N_EDGES) {
        int d = dst[e];
        unsigned long long inc = (1ull << 40)
            + (unsigned long long)(uint)(ew[e]*8388608.f + 0.5f);
        unsigned long long old = atomicAdd(&pk[d], inc);
        rank[e] = (int)(old >> 40);
    }
}

// scan phase A (+ fused prep): per-1024 chunk exclusive scan + chunk totals
__global__ __launch_bounds__(1024) void scan_a(const unsigned long long* __restrict__ pk,
                                               int* __restrict__ rowptr,
                                               int* __restrict__ bsum,
                                               float* __restrict__ inv_cnt,
                                               float* __restrict__ dis)
{
    __shared__ int wsum[16];
    int tid = threadIdx.x;
    int i = blockIdx.x*1024 + tid;
    int v = 0;
    if (i < N_NODES) {
        unsigned long long u = pk[i];
        v = (int)(u >> 40);
        float dw = (float)(u & ((1ull<<40)-1)) * (1.f/8388608.f);
        inv_cnt[i] = 1.f / (float)max(v, 1);
        dis[i] = rsqrtf(dw + 1.f);   // +1 self-loop weight; always > 0
    }
    int lane = tid & 63, wid = tid >> 6;
    int incl = v;
    #pragma unroll
    for (int off = 1; off < 64; off <<= 1) {
        int t = __shfl_up(incl, off);
        if (lane >= off) incl += t;
    }
    if (lane == 63) wsum[wid] = incl;
    __syncthreads();
    if (wid == 0 && lane < 16) {
        int s = wsum[lane];
        #pragma unroll
        for (int off = 1; off < 16; off <<= 1) {
            int t = __shfl_up(s, off);
            if (lane >= off) s += t;
        }
        wsum[lane] = s;
    }
    __syncthreads();
    int base = (wid > 0) ? wsum[wid-1] : 0;
    if (i < N_NODES) rowptr[i] = base + incl - v;
    if (tid == 1023) bsum[blockIdx.x] = base + incl;
}

// scan phase C (fused B): every block re-scans the 49 chunk totals in wave 0
__global__ __launch_bounds__(256) void scan_c(int* __restrict__ rowptr,
                                              const int* __restrict__ bsum)
{
    __shared__ int boff[64];
    int tid = threadIdx.x;
    if (tid < 64) {
        const int NC = (N_NODES + 1023) >> 10;   // 49
        int v = (tid < NC) ? bsum[tid] : 0;
        int incl = v;
        #pragma unroll
        for (int off = 1; off < 64; off <<= 1) {
            int t = __shfl_up(incl, off);
            if (tid >= off) incl += t;
        }
        boff[tid] = incl - v;   // exclusive; boff[NC] = grand total
    }
    __syncthreads();
    int i = blockIdx.x*256 + tid;
    if (i < N_NODES) rowptr[i] += boff[i >> 10];
    else if (i == N_NODES) rowptr[i] = boff[(N_NODES + 1023) >> 10];
}

// scatter (no atomics): pos = rowptr[dst] + rank; edge = {src, ew*dis[src]}
__global__ void scatter_kernel(const int* __restrict__ src, const int* __restrict__ dst,
                               const float* __restrict__ ew, const float* __restrict__ dis,
                               const int* __restrict__ rowptr, const int* __restrict__ rank,
                               int2* __restrict__ edge)
{
    int e = blockIdx.x*256 + threadIdx.x;
    if (e < N_EDGES) {
        int d = dst[e];
        int s = src[e];
        int pos = rowptr[d] + rank[e];
        edge[pos] = make_int2(s, __float_as_int(ew[e] * dis[s]));
    }
}

// ---------------- aggregation (bf16 h, one wave per node, lane = 2 feats) ----------------
__global__ __launch_bounds__(256) void sage_agg(
    const ushort* __restrict__ h, int ldh, int D2,
    const int* __restrict__ rowptr, const int2* __restrict__ edge,
    const float* __restrict__ inv_cnt,
    ushort* __restrict__ out, int ldo)
{
    int w = threadIdx.x >> 6, l = threadIdx.x & 63;
    int n = blockIdx.x*4 + w;
    if (n >= N_NODES) return;
    int beg = rowptr[n], end = rowptr[n+1];
    bool act = l < D2;
    int off = 2*l;
    float ax = 0.f, ay = 0.f;
    int j = beg;
    for (; j + 7 < end; j += 8) {
        int ss[8];
        #pragma unroll
        for (int q = 0; q < 8; q++) ss[q] = edge[j+q].x;
        if (act) {
            uint u[8];
            #pragma unroll
            for (int q = 0; q < 8; q++) u[q] = *(const uint*)(h + (size_t)ss[q]*ldh + off);
            #pragma unroll
            for (int q = 0; q < 8; q++) {
                ax += __uint_as_float(u[q]<<16);
                ay += __uint_as_float(u[q] & 0xffff0000u);
            }
        }
    }
    for (; j < end; j++) {
        int s = edge[j].x;
        if (act) {
            uint u = *(const uint*)(h + (size_t)s*ldh + off);
            ax += __uint_as_float(u<<16);
            ay += __uint_as_float(u & 0xffff0000u);
        }
    }
    if (act) {
        float ic = inv_cnt[n];
        uint o = (uint)f2b(ax*ic) | ((uint)f2b(ay*ic) << 16);
        *(uint*)(out + (size_t)n*ldo + off) = o;
    }
}

__global__ __launch_bounds__(256) void gcn_agg(
    const ushort* __restrict__ h,
    const int* __restrict__ rowptr, const int2* __restrict__ edge,
    const float* __restrict__ dis,
    ushort* __restrict__ out)
{
    int w = threadIdx.x >> 6, l = threadIdx.x & 63;
    int n = blockIdx.x*4 + w;
    if (n >= N_NODES) return;
    int beg = rowptr[n], end = rowptr[n+1];
    int off = 2*l;
    float ax = 0.f, ay = 0.f;
    int j = beg;
    for (; j + 7 < end; j += 8) {
        int2 ee[8];
        #pragma unroll
        for (int q = 0; q < 8; q++) ee[q] = edge[j+q];
        uint u[8];
        #pragma unroll
        for (int q = 0; q < 8; q++) u[q] = *(const uint*)(h + (size_t)ee[q].x*128 + off);
        #pragma unroll
        for (int q = 0; q < 8; q++) {
            float wq = __int_as_float(ee[q].y);
            ax += wq*__uint_as_float(u[q]<<16);
            ay += wq*__uint_as_float(u[q] & 0xffff0000u);
        }
    }
    for (; j < end; j++) {
        int2 e = edge[j];
        float wj = __int_as_float(e.y);
        uint u = *(const uint*)(h + (size_t)e.x*128 + off);
        ax += wj*__uint_as_float(u<<16);
        ay += wj*__uint_as_float(u & 0xffff0000u);
    }
    float dn = dis[n];
    uint us = *(const uint*)(h + (size_t)n*128 + off);
    float sx = __uint_as_float(us<<16), sy = __uint_as_float(us & 0xffff0000u);
    float rx = dn*ax + dn*dn*sx;
    float ry = dn*ay + dn*dn*sy;
    uint o = (uint)f2b(rx) | ((uint)f2b(ry) << 16);
    *(uint*)(out + (size_t)n*128 + off) = o;
}

// ---------------- weight prep: all 6 weights in one kernel ----------------
__device__ __forceinline__ void wprep(int idx, int K1, int KT, int NOUT,
                                      const float* __restrict__ w1,
                                      const float* __restrict__ w2,
                                      ushort* __restrict__ dst)
{
    int k = idx / NOUT, c = idx - k*NOUT;
    float v = (k < K1) ? w1[idx] : w2[idx - K1*NOUT];
    dst[c*KT + k] = f2b(v);
}

__global__ void prep_w_all(
    const float* __restrict__ c1_wl, const float* __restrict__ c1_wr,
    const float* __restrict__ c2_w,  const float* __restrict__ c3_wl,
    const float* __restrict__ c3_wr, const float* __restrict__ c4_w,
    const float* __restrict__ fu_w,  const float* __restrict__ cl_w1,
    ushort* __restrict__ wt1, ushort* __restrict__ wt2, ushort* __restrict__ wt3,
    ushort* __restrict__ wt4, ushort* __restrict__ wtF, ushort* __restrict__ wtC1)
{
    int idx = blockIdx.x*256 + threadIdx.x;
    if      (idx <  24576) wprep(idx,          96, 192, 128, c1_wl, c1_wr, wt1);
    else if (idx <  40960) wprep(idx - 24576, 128, 128, 128, c2_w,  c2_w,  wt2);
    else if (idx <  73728) wprep(idx - 40960, 128, 256, 128, c3_wl, c3_wr, wt3);
    else if (idx <  90112) wprep(idx - 73728, 128, 128, 128, c4_w,  c4_w,  wt4);
    else if (idx < 122880) wprep(idx - 90112, 128, 256, 128, fu_w,  fu_w + 16384, wtF);
    else if (idx < 131072) wprep(idx - 122880,128, 128,  64, cl_w1, cl_w1, wtC1);
}

// ---------------- MFMA GEMM: C = [A1|A2] @ W + bias (bf16 in, bf16 out, fp32 acc) -----
template<int KT, int K1, int NOUT, bool RELU, bool STATS>
__global__ __launch_bounds__(256, 2) void gemm_mfma(
    const ushort* __restrict__ A1, int lda1,
    const ushort* __restrict__ A2, int lda2,
    const ushort* __restrict__ Wt,
    const float* __restrict__ bias,
    ushort* __restrict__ C, int ldc,
    float* __restrict__ stats)
{
    constexpr int NCF = NOUT/16;
    constexpr int NKS = KT/32;
    __shared__ float red[2][NOUT];
    int tid = threadIdx.x;
    int w = tid >> 6, l = tid & 63;
    int l15 = l & 15, l4 = l >> 4;
    int r0 = blockIdx.x*128 + w*32;

    const ushort* pa1[2]; const ushort* pa2[2];
    #pragma unroll
    for (int rf = 0; rf < 2; rf++) {
        int rc = min(r0 + rf*16 + l15, N_NODES-1);
        pa1[rf] = A1 + (size_t)rc*lda1 + 8*l4;
        pa2[rf] = A2 + (size_t)rc*lda2 + 8*l4;
    }
    const ushort* pw = Wt + (size_t)l15*KT + 8*l4;

    f32x4 acc[2][NCF];
    #pragma unroll
    for (int rf = 0; rf < 2; rf++)
        #pragma unroll
        for (int cf = 0; cf < NCF; cf++)
            acc[rf][cf] = (f32x4){0.f, 0.f, 0.f, 0.f};

    #pragma unroll
    for (int ks = 0; ks < NKS; ks++) {
        const int k0 = ks*32;
        s16x8 a[2];
        #pragma unroll
        for (int rf = 0; rf < 2; rf++) {
            const ushort* p = (k0 < K1) ? (pa1[rf] + k0) : (pa2[rf] + (k0 - K1));
            a[rf] = *(const s16x8*)p;
        }
        s16x8 b[NCF];
        #pragma unroll
        for (int cf = 0; cf < NCF; cf++)
            b[cf] = *(const s16x8*)(pw + (size_t)cf*16*KT + k0);
        #pragma unroll
        for (int rf = 0; rf < 2; rf++)
            #pragma unroll
            for (int cf = 0; cf < NCF; cf++)
                acc[rf][cf] = __builtin_amdgcn_mfma_f32_16x16x32_bf16(a[rf], b[cf], acc[rf][cf], 0, 0, 0);
    }

    float s1l[NCF], s2l[NCF];
    #pragma unroll
    for (int cf = 0; cf < NCF; cf++) { s1l[cf] = 0.f; s2l[cf] = 0.f; }

    #pragma unroll
    for (int cf = 0; cf < NCF; cf++) {
        int colc = cf*16 + l15;
        float bv = bias[colc];
        #pragma unroll
        for (int rf = 0; rf < 2; rf++) {
            int rb = r0 + rf*16 + l4*4;
            #pragma unroll
            for (int reg = 0; reg < 4; reg++) {
                int r = rb + reg;
                if (r < N_NODES) {
                    float v = acc[rf][cf][reg] + bv;
                    if (RELU) v = fmaxf(v, 0.f);
                    C[(size_t)r*ldc + colc] = f2b(v);
                    if (STATS) { s1l[cf] += v; s2l[cf] += v*v; }
                }
            }
        }
    }

    if (STATS) {
        for (int i = tid; i < 2*NOUT; i += 256) (&red[0][0])[i] = 0.f;
        __syncthreads();
        #pragma unroll
        for (int cf = 0; cf < NCF; cf++) {
            atomicAdd(&red[0][cf*16 + l15], s1l[cf]);
            atomicAdd(&red[1][cf*16 + l15], s2l[cf]);
        }
        __syncthreads();
        for (int i = tid; i < NOUT; i += 256) {
            atomicAdd(&stats[i], red[0][i]);
            atomicAdd(&stats[NOUT+i], red[1][i]);
        }
    }
}

// ---------------- BN + ReLU in place on bf16 (N x 128) ----------------
__global__ __launch_bounds__(256) void bnrelu_kernel(
    ushort* __restrict__ h, const float* __restrict__ stats,
    const float* __restrict__ g, const float* __restrict__ b)
{
    __shared__ float sc[128], sh[128];
    int tid = threadIdx.x;
    if (tid < 128) {
        float mu  = stats[tid] * (1.f/N_NODES);
        float var = stats[128+tid] * (1.f/N_NODES) - mu*mu;
        float s = g[tid] * rsqrtf(var + EPS_BN);
        sc[tid] = s;
        sh[tid] = b[tid] - mu*s;
    }
    __syncthreads();
    const int total = N_NODES * 16;   // uint4 chunks of 8 bf16
    for (int i = blockIdx.x*256 + tid; i < total; i += gridDim.x*256) {
        uint4 u = ((const uint4*)h)[i];
        int c = (i & 15) * 8;
        float v0 = __uint_as_float(u.x<<16),  v1 = __uint_as_float(u.x & 0xffff0000u);
        float v2 = __uint_as_float(u.y<<16),  v3 = __uint_as_float(u.y & 0xffff0000u);
        float v4 = __uint_as_float(u.z<<16),  v5 = __uint_as_float(u.z & 0xffff0000u);
        float v6 = __uint_as_float(u.w<<16),  v7 = __uint_as_float(u.w & 0xffff0000u);
        v0 = fmaxf(v0*sc[c+0] + sh[c+0], 0.f);
        v1 = fmaxf(v1*sc[c+1] + sh[c+1], 0.f);
        v2 = fmaxf(v2*sc[c+2] + sh[c+2], 0.f);
        v3 = fmaxf(v3*sc[c+3] + sh[c+3], 0.f);
        v4 = fmaxf(v4*sc[c+4] + sh[c+4], 0.f);
        v5 = fmaxf(v5*sc[c+5] + sh[c+5], 0.f);
        v6 = fmaxf(v6*sc[c+6] + sh[c+6], 0.f);
        v7 = fmaxf(v7*sc[c+7] + sh[c+7], 0.f);
        u.x = (uint)f2b(v0) | ((uint)f2b(v1)<<16);
        u.y = (uint)f2b(v2) | ((uint)f2b(v3)<<16);
        u.z = (uint)f2b(v4) | ((uint)f2b(v5)<<16);
        u.w = (uint)f2b(v6) | ((uint)f2b(v7)<<16);
        ((uint4*)h)[i] = u;
    }
}

// ---------------- classifier head 2: out = hc(N,64)bf16 @ w2(64,10) + b2 -> fp32 ----------
__global__ __launch_bounds__(128) void cl2_kernel(
    const ushort* __restrict__ hc, const float* __restrict__ w2,
    const float* __restrict__ b2, float* __restrict__ out)
{
    __shared__ float tile[128][65];
    __shared__ float wl[640];
    __shared__ float bl[16];
    __shared__ float ol[1280];
    int tid = threadIdx.x;
    int base = blockIdx.x * 128;
    int nv = min(128, N_NODES - base);
    for (int i = tid; i < 640; i += 128) wl[i] = w2[i];
    if (tid < 10) bl[tid] = b2[tid];
    for (int i = tid; i < nv*64; i += 128) {
        int r = i >> 6, c = i & 63;
        tile[r][c] = b2f(hc[(size_t)base*64 + i]);
    }
    __syncthreads();
    if (tid < nv) {
        float o[10];
        #pragma unroll
        for (int j = 0; j < 10; j++) o[j] = bl[j];
        #pragma unroll 4
        for (int k = 0; k < 64; k++) {
            float hv = tile[tid][k];
            #pragma unroll
            for (int j = 0; j < 10; j++) o[j] += hv * wl[k*10+j];
        }
        #pragma unroll
        for (int j = 0; j < 10; j++) ol[tid*10+j] = o[j];
    }
    __syncthreads();
    for (int i = tid; i < nv*10; i += 128) out[(size_t)base*10 + i] = ol[i];
}

// ---------------- launch ----------------
extern "C" void kernel_launch(void* const* d_in, const int* in_sizes, int n_in,
                              void* d_out, int out_size, void* d_ws, size_t ws_size,
                              hipStream_t stream)
{
    const float* x     = (const float*)d_in[0];
    const int*   ei    = (const int*)  d_in[1];
    const float* ew    = (const float*)d_in[2];
    const float* sp_w1 = (const float*)d_in[3];
    const float* sp_b1 = (const float*)d_in[4];
    const float* sp_w2 = (const float*)d_in[5];
    const float* sp_b2 = (const float*)d_in[6];
    const float* fe_w  = (const float*)d_in[7];
    const float* fe_b  = (const float*)d_in[8];
    const float* c1_wl = (const float*)d_in[9];
    const float* c1_wr = (const float*)d_in[10];
    const float* c1_b  = (const float*)d_in[11];
    const float* c2_w  = (const float*)d_in[12];
    const float* c2_b  = (const float*)d_in[13];
    const float* c3_wl = (const float*)d_in[14];
    const float* c3_wr = (const float*)d_in[15];
    const float* c3_b  = (const float*)d_in[16];
    const float* c4_w  = (const float*)d_in[17];
    const float* c4_b  = (const float*)d_in[18];
    const float* bn_g  = (const float*)d_in[19];
    const float* bn_b  = (const float*)d_in[20];
    const float* fu_w  = (const float*)d_in[21];
    const float* fu_b  = (const float*)d_in[22];
    const float* cl_w1 = (const float*)d_in[23];
    const float* cl_b1 = (const float*)d_in[24];
    const float* cl_w2 = (const float*)d_in[25];
    const float* cl_b2 = (const float*)d_in[26];
    const int* src = ei;
    const int* dst = ei + N_EDGES;
    float* out = (float*)d_out;

    char* p = (char*)d_ws;
    auto alloc = [&](size_t bytes) -> char* {
        char* r = p;
        p += (bytes + 255) & ~(size_t)255;
        return r;
    };
    // zeroed region: pk, stats
    char* zero_base = p;
    unsigned long long* pk = (unsigned long long*)alloc(N_NODES*8);
    float* stats = (float*)alloc(4*256*4);
    size_t zero_bytes = (size_t)(p - zero_base);
    int*   rowptr  = (int*)  alloc((N_NODES+1)*4);
    int*   bsum    = (int*)  alloc(64*4);
    int*   rank    = (int*)  alloc((size_t)N_EDGES*4);
    int2*  edge    = (int2*) alloc((size_t)N_EDGES*8);
    float* inv_cnt = (float*)alloc(N_NODES*4);
    float* dis     = (float*)alloc(N_NODES*4);
    ushort* wt1  = (ushort*)alloc(192*128*2);
    ushort* wt2  = (ushort*)alloc(128*128*2);
    ushort* wt3  = (ushort*)alloc(256*128*2);
    ushort* wt4  = (ushort*)alloc(128*128*2);
    ushort* wtF  = (ushort*)alloc(256*128*2);
    ushort* wtC1 = (ushort*)alloc(128*64*2);
    ushort* h0  = (ushort*)alloc((size_t)N_NODES*96*2);
    ushort* AGG = (ushort*)alloc((size_t)N_NODES*128*2);
    ushort* H1  = (ushort*)alloc((size_t)N_NODES*128*2);
    ushort* H2  = (ushort*)alloc((size_t)N_NODES*128*2);
    ushort* H3  = (ushort*)alloc((size_t)N_NODES*128*2);
    ushort* H4 = H3;   // H3 dead after conv4 aggregation
    ushort* HF = H1;   // H1 dead after conv2 aggregation
    ushort* HC = h0;   // h0 dead after conv1 GEMM (N*64 <= N*96)

    hipMemsetAsync(zero_base, 0, zero_bytes, stream);

    prep_w_all<<<512, 256, 0, stream>>>(c1_wl, c1_wr, c2_w, c3_wl, c3_wr, c4_w, fu_w, cl_w1,
                                        wt1, wt2, wt3, wt4, wtF, wtC1);

    encoder_kernel<<<391, 128, 0, stream>>>(x, sp_w1, sp_b1, sp_w2, sp_b2, fe_w, fe_b, h0);

    // CSR
    deg_kernel<<<(N_EDGES+255)/256, 256, 0, stream>>>(dst, ew, pk, rank);
    scan_a<<<(N_NODES+1023)/1024, 1024, 0, stream>>>(pk, rowptr, bsum, inv_cnt, dis);
    scan_c<<<(N_NODES+1+255)/256, 256, 0, stream>>>(rowptr, bsum);
    scatter_kernel<<<(N_EDGES+255)/256, 256, 0, stream>>>(src, dst, ew, dis, rowptr, rank, edge);

    const int GG = (N_NODES + 127) / 128;   // 391
    const int GA = (N_NODES + 3) / 4;       // 12500

    // conv1 (SAGE, 96 -> 128)
    sage_agg<<<GA, 256, 0, stream>>>(h0, 96, 48, rowptr, edge, inv_cnt, AGG, 96);
    gemm_mfma<192,96,128,false,true><<<GG, 256, 0, stream>>>(AGG, 96, h0, 96, wt1, c1_b, H1, 128, stats + 0);
    bnrelu_kernel<<<1024, 256, 0, stream>>>(H1, stats + 0, bn_g + 0, bn_b + 0);

    // conv2 (GCN, 128 -> 128)
    gcn_agg<<<GA, 256, 0, stream>>>(H1, rowptr, edge, dis, AGG);
    gemm_mfma<128,128,128,false,true><<<GG, 256, 0, stream>>>(AGG, 128, AGG, 128, wt2, c2_b, H2, 128, stats + 256);
    bnrelu_kernel<<<1024, 256, 0, stream>>>(H2, stats + 256, bn_g + 128, bn_b + 128);

    // conv3 (SAGE, 128 -> 128)
    sage_agg<<<GA, 256, 0, stream>>>(H2, 128, 64, rowptr, edge, inv_cnt, AGG, 128);
    gemm_mfma<256,128,128,false,true><<<GG, 256, 0, stream>>>(AGG, 128, H2, 128, wt3, c3_b, H3, 128, stats + 512);
    bnrelu_kernel<<<1024, 256, 0, stream>>>(H3, stats + 512, bn_g + 256, bn_b + 256);

    // conv4 (GCN, 128 -> 128)
    gcn_agg<<<GA, 256, 0, stream>>>(H3, rowptr, edge, dis, AGG);
    gemm_mfma<128,128,128,false,true><<<GG, 256, 0, stream>>>(AGG, 128, AGG, 128, wt4, c4_b, H4, 128, stats + 768);
    bnrelu_kernel<<<1024, 256, 0, stream>>>(H4, stats + 768, bn_g + 384, bn_b + 384);

    // fuse: HF = [H2, H4] @ fu_w + fu_b
    gemm_mfma<256,128,128,false,false><<<GG, 256, 0, stream>>>(H2, 128, H4, 128, wtF, fu_b, HF, 128, nullptr);
    // cl1: HC = relu(HF @ cl_w1 + cl_b1)
    gemm_mfma<128,128,64,true,false><<<GG, 256, 0, stream>>>(HF, 128, HF, 128, wtC1, cl_b1, HC, 64, nullptr);
    // cl2
    cl2_kernel<<<391, 128, 0, stream>>>(HC, cl_w2, cl_b2, out);
}